// Round 5
// baseline (81.898 us; speedup 1.0000x reference)
//
#include <hip/hip_runtime.h>

// BoundaryLoss: mean(sigmoid(logits) * EDT2D(target)), B=8, H=W=256.
//
// Structure: 2 dispatches (fused row+column pass, final reduce).
// Evidence so far (rounds 0-3): timed window = 256 MiB harness poison fill
// (~41 us, untouchable) + kernel bodies (~7 us) + ~5 us per dispatch gap.
// In-kernel cross-block sync (grid.sync / threadfence+ticket) costs far more
// than a dispatch boundary on this 8-XCD part (round 2: ~50 us per sync).
// => optimize by DELETING dispatches with block-local redundant work.
//
// Fused pass: block -> (batch b, 4 columns w0..w0+3). Thread t stages row t
// of target as a 256-bit bitmask in registers (64 int4 loads, sequential per
// thread -> L1-reuses each 128B line 8x; image is L2/L3-resident, 64 blocks
// share it). Nearest-set-bit left/right of w0 via clz/ffs + incremental
// update across the 4 adjacent columns gives the EXACT integer row distance
// (bit-identical to the old wave-scan row kernel), so
//   q[c][t] = t^2 + (d<=255 ? d*d : fl(1e12))
// is bit-identical to before -> absmax stays 0.0.
// Then the O(H^2) column EDT (strength-reduced min_j j^2+m_j-2ij, q staged
// in LDS, broadcast ds_read_b128 feeds 16 fma+min per float4), sigmoid
// weighting, block reduce. Final kernel: deterministic 512-term reduce in
// the exact reference fp order.

#define BIGF 1000000.0f
#define BIG2 (BIGF * BIGF)   // fp32 rounding of 1e12, same as ref's BIG*BIG
#define BIGI (1 << 20)

constexpr int B = 8;
constexpr int H = 256;
constexpr int W = 256;
constexpr int NPIX = B * H * W;   // 524288

__device__ __forceinline__ float block_reduce_sum_256(float v) {
    #pragma unroll
    for (int off = 32; off > 0; off >>= 1)
        v += __shfl_down(v, off, 64);
    __shared__ float s[4];
    const int lane = threadIdx.x & 63;
    const int wid  = threadIdx.x >> 6;
    if (lane == 0) s[wid] = v;
    __syncthreads();
    if (wid == 0) {
        v = (lane < 4) ? s[lane] : 0.0f;
        v += __shfl_down(v, 2, 64);
        v += __shfl_down(v, 1, 64);
    }
    return v;  // valid on thread 0
}

// 16 candidates (4 outputs x 4 j's) per LDS float4.
__device__ __forceinline__ void upd16(const float4 m, float j0,
                                      float n0, float n1, float n2, float n3,
                                      float& b0, float& b1, float& b2, float& b3) {
    const float j1 = j0 + 1.0f, j2 = j0 + 2.0f, j3 = j0 + 3.0f;
    {
        const float c0 = fmaf(n0, j0, m.x), c1 = fmaf(n0, j1, m.y);
        const float c2 = fmaf(n0, j2, m.z), c3 = fmaf(n0, j3, m.w);
        b0 = fminf(b0, fminf(fminf(c0, c1), fminf(c2, c3)));
    }
    {
        const float c0 = fmaf(n1, j0, m.x), c1 = fmaf(n1, j1, m.y);
        const float c2 = fmaf(n1, j2, m.z), c3 = fmaf(n1, j3, m.w);
        b1 = fminf(b1, fminf(fminf(c0, c1), fminf(c2, c3)));
    }
    {
        const float c0 = fmaf(n2, j0, m.x), c1 = fmaf(n2, j1, m.y);
        const float c2 = fmaf(n2, j2, m.z), c3 = fmaf(n2, j3, m.w);
        b2 = fminf(b2, fminf(fminf(c0, c1), fminf(c2, c3)));
    }
    {
        const float c0 = fmaf(n3, j0, m.x), c1 = fmaf(n3, j1, m.y);
        const float c2 = fmaf(n3, j2, m.z), c3 = fmaf(n3, j3, m.w);
        b3 = fminf(b3, fminf(fminf(c0, c1), fminf(c2, c3)));
    }
}

// Fused pass: 512 blocks x 256 thr; block -> (batch b, columns w0..w0+3).
__global__ __launch_bounds__(256) void fused_pass_kernel(
        const float* __restrict__ logits, const int* __restrict__ target,
        float* __restrict__ partials) {
    __shared__ float s_q[4][256];
    const int t  = threadIdx.x;
    const int b  = blockIdx.x >> 6;
    const int w0 = (blockIdx.x & 63) << 2;

    // ---- Phase A: row-t bitmask in registers (4 x u64 = pixels 0..255) ----
    {
        const int* rowp = target + (b * H + t) * W;
        unsigned long long wb[4];
        #pragma unroll
        for (int g = 0; g < 4; ++g) {
            unsigned long long acc = 0ull;
            #pragma unroll
            for (int k = 0; k < 16; ++k) {
                const int4 tv = *(const int4*)(rowp + (((g << 4) + k) << 2));
                unsigned long long nib =
                    (tv.x > 0 ? 1ull : 0ull) | (tv.y > 0 ? 2ull : 0ull) |
                    (tv.z > 0 ? 4ull : 0ull) | (tv.w > 0 ? 8ull : 0ull);
                acc |= nib << (k << 2);
            }
            wb[g] = acc;
        }

        // nearest set bit <= w0 (L) and >= w0+3 (R3); exact, branchless.
        const int kw     = w0 >> 6;                    // wave-uniform 0..3
        const int bshift = w0 & 63;                    // wave-uniform, <= 60
        const unsigned long long mlo = (2ull << bshift) - 1ull;   // bits 0..bshift
        const unsigned long long mhi = (~0ull) << (bshift + 3);   // bits bshift+3..63

        int L = -BIGI;
        #pragma unroll
        for (int k = 0; k < 4; ++k) {   // ascending: later nonzero word wins
            const unsigned long long vl =
                (k < kw) ? wb[k] : ((k == kw) ? (wb[k] & mlo) : 0ull);
            const int candL = (k << 6) + 63 - __clzll((long long)vl);
            L = vl ? candL : L;
        }
        int R3 = BIGI;
        #pragma unroll
        for (int k = 3; k >= 0; --k) {  // descending: smaller nonzero word wins
            const unsigned long long vr =
                (k > kw) ? wb[k] : ((k == kw) ? (wb[k] & mhi) : 0ull);
            const int candR = (k << 6) + __ffsll((unsigned long long)vr) - 1;
            R3 = vr ? candR : R3;
        }

        // incremental across the 4 adjacent columns (all in word kw)
        const unsigned long long wkw =
            (kw & 2) ? ((kw & 1) ? wb[3] : wb[2]) : ((kw & 1) ? wb[1] : wb[0]);
        const unsigned bit0 = (unsigned)(wkw >> bshift)       & 1u;
        const unsigned bit1 = (unsigned)(wkw >> (bshift + 1)) & 1u;
        const unsigned bit2 = (unsigned)(wkw >> (bshift + 2)) & 1u;
        const unsigned bit3 = (unsigned)(wkw >> (bshift + 3)) & 1u;

        const int L0 = L;                        // L(w0) (includes bit w0)
        const int L1 = bit1 ? (w0 + 1) : L0;
        const int L2 = bit2 ? (w0 + 2) : L1;
        const int L3 = bit3 ? (w0 + 3) : L2;
        const int R3c = R3;                      // Rt(w0+3)
        const int R2 = bit2 ? (w0 + 2) : R3c;
        const int R1 = bit1 ? (w0 + 1) : R2;
        const int R0 = bit0 ? (w0 + 0) : R1;

        const int d0 = min(w0     - L0, R0 - w0);
        const int d1 = min(w0 + 1 - L1, R1 - (w0 + 1));
        const int d2 = min(w0 + 2 - L2, R2 - (w0 + 2));
        const int d3 = min(w0 + 3 - L3, R3c - (w0 + 3));

        const float fj  = (float)t;
        const float fj2 = fj * fj;               // exact (< 2^24)
        const float f0 = (float)d0, f1 = (float)d1;
        const float f2 = (float)d2, f3 = (float)d3;
        s_q[0][t] = fj2 + ((d0 > 255) ? BIG2 : f0 * f0);
        s_q[1][t] = fj2 + ((d1 > 255) ? BIG2 : f1 * f1);
        s_q[2][t] = fj2 + ((d2 > 255) ? BIG2 : f2 * f2);
        s_q[3][t] = fj2 + ((d3 > 255) ? BIG2 : f3 * f3);
    }
    __syncthreads();

    // ---- Phase B: column EDT + sigmoid + block reduce (unchanged) ----
    const int lane = t & 63;
    const int wv   = t >> 6;
    const float i0f = (float)lane,         i1f = (float)(lane + 64);
    const float i2f = (float)(lane + 128), i3f = (float)(lane + 192);
    const float n0 = -2.0f * i0f, n1 = -2.0f * i1f;
    const float n2 = -2.0f * i2f, n3 = -2.0f * i3f;
    float b0 = 4e12f, b1 = 4e12f, b2 = 4e12f, b3 = 4e12f;

    float fjv = 0.0f;
    #pragma unroll 4
    for (int jv = 0; jv < 64; ++jv, fjv += 4.0f) {
        const float4 m = *(const float4*)&s_q[wv][jv << 2];
        upd16(m, fjv, n0, n1, n2, n3, b0, b1, b2, b3);
    }

    const int wcol = w0 + wv;
    const int base = (b * H + lane) * W + wcol;
    float acc;
    {
        const float dist = sqrtf(fmaf(i0f, i0f, b0));
        const float x = logits[base];
        acc = dist / (1.0f + expf(-x));
    }
    {
        const float dist = sqrtf(fmaf(i1f, i1f, b1));
        const float x = logits[base + 64 * W];
        acc += dist / (1.0f + expf(-x));
    }
    {
        const float dist = sqrtf(fmaf(i2f, i2f, b2));
        const float x = logits[base + 128 * W];
        acc += dist / (1.0f + expf(-x));
    }
    {
        const float dist = sqrtf(fmaf(i3f, i3f, b3));
        const float x = logits[base + 192 * W];
        acc += dist / (1.0f + expf(-x));
    }

    const float s = block_reduce_sum_256(acc);
    if (t == 0) partials[blockIdx.x] = s;
}

__global__ __launch_bounds__(256) void final_reduce_kernel(
        const float* __restrict__ partials, float* __restrict__ out,
        int n, float scale) {
    float v = 0.0f;
    for (int idx = threadIdx.x; idx < n; idx += 256)
        v += partials[idx];
    v = block_reduce_sum_256(v);
    if (threadIdx.x == 0) out[0] = v * scale;
}

extern "C" void kernel_launch(void* const* d_in, const int* in_sizes, int n_in,
                              void* d_out, int out_size, void* d_ws, size_t ws_size,
                              hipStream_t stream) {
    const float* logits = (const float*)d_in[0];
    const int*   target = (const int*)d_in[1];

    float* partials = (float*)d_ws;     // 512 floats

    fused_pass_kernel<<<B * W / 4, 256, 0, stream>>>(logits, target, partials);
    final_reduce_kernel<<<1, 256, 0, stream>>>(partials, (float*)d_out,
                                               B * W / 4, 1.0f / (float)NPIX);
}